// Round 13
// baseline (43.656 us; speedup 1.0000x reference)
//
#include <hip/hip_runtime.h>
#include <math.h>

#define NUM_CLASSES 80
#define OBJ_BLOCKS 1536                 // 3 scales x 16 batch x 32 targets
#define NEG0_BLOCKS 150                 // 76800 float4 / 512 (exact)
#define NEG1_BLOCKS 38                  // ceil(19200 / 512)
#define NEG2_BLOCKS 10                  // ceil(4800 / 512)
#define NEG_BLOCKS (NEG0_BLOCKS + NEG1_BLOCKS + NEG2_BLOCKS)   // 198
#define PRODUCERS (OBJ_BLOCKS + NEG_BLOCKS)                    // 1734
#define NCELLS 21                       // 3 scales x {xy,wh,cls,pos,corr,nobj,neg}
#define NSTRIPE 8                       // contention stripes per cell

// ---- math helpers (match jax.nn.log_sigmoid / sigmoid in f32) ----
__device__ __forceinline__ float softplusf_(float x) {
    return x > 0.f ? x + log1pf(expf(-x)) : log1pf(expf(x));
}
__device__ __forceinline__ float sigmoidf_(float x) {
    return 1.f / (1.f + expf(-x));
}
// focal_bce(x, t=0) = softplus(x) * sigmoid(x)^2
__device__ __forceinline__ float focal0(float x) {
    float s = sigmoidf_(x);
    return softplusf_(x) * s * s;
}
// focal_bce(x, t=1) = softplus(-x) * sigmoid(-x)^2
__device__ __forceinline__ float focal1(float x) {
    float s = sigmoidf_(-x);
    return softplusf_(-x) * s * s;
}

// ---- device-global accumulators (module .bss: zero at load, never poisoned;
// finalizing block resets to 0 each call -> replay-deterministic).
// R12 lesson: ~480 same-line RMWs serialized ~10us. Fix: 8 stripes per cell,
// each on its own 128B line -> hottest line ~60 RMWs.
__device__ float    g_acc[NCELLS][NSTRIPE][32];   // only [c][j][0] used
__device__ unsigned g_cnt[8][32];                 // striped leaf counters
__device__ unsigned g_master[32];                 // leaf-last -> master

__device__ __forceinline__ float ld_llc(const float* p) {
    return __hip_atomic_load(p, __ATOMIC_RELAXED, __HIP_MEMORY_SCOPE_AGENT);
}
__device__ __forceinline__ void st_llc(float* p, float v) {
    __hip_atomic_store(p, v, __ATOMIC_RELAXED, __HIP_MEMORY_SCOPE_AGENT);
}

// Completion chain (R10/R12-proven): producer wave drains its own vector ops
// (s_waitcnt vmcnt(0)) -> relaxed fetch_add on leaf counter (bid&7; distinct
// lines). Leaf-last bumps master; master-last knows ALL producers' atomics
// are at the LLC -> finalizes inline. No fences (R9: agent-release = L2
// writeback storm), no single hot counter (R7), no spin block (R10 tail).
__device__ __forceinline__ void finish_block(int bid, float* out) {
    asm volatile("s_waitcnt vmcnt(0)" ::: "memory");
    const int k = bid & 7;
    const unsigned expk = (k < 6) ? 217u : 216u;   // 1734 = 6*217 + 2*216
    const unsigned old = __hip_atomic_fetch_add(
        &g_cnt[k][0], 1u, __ATOMIC_RELAXED, __HIP_MEMORY_SCOPE_AGENT);
    if (old != expk - 1u) return;
    const unsigned mold = __hip_atomic_fetch_add(
        &g_master[0], 1u, __ATOMIC_RELAXED, __HIP_MEMORY_SCOPE_AGENT);
    if (mold != 7u) return;

    // ===== global last block: finalize =====
    float a[NCELLS];
    #pragma unroll
    for (int c = 0; c < NCELLS; ++c) {
        float v = 0.f;
        #pragma unroll
        for (int j = 0; j < NSTRIPE; ++j) v += ld_llc(&g_acc[c][j][0]);
        a[c] = v;
    }

    float total = 0.f;
    #pragma unroll
    for (int s = 0; s < 3; ++s) {
        const float sxy  = a[s * 7 + 0];
        const float swh  = a[s * 7 + 1];
        const float scls = a[s * 7 + 2];
        const float spos = a[s * 7 + 3];
        const float scor = a[s * 7 + 4];
        const float nobj = a[s * 7 + 5];
        const float negs = a[s * 7 + 6];
        const float Ns = (s == 0) ? (float)(16 * 3 * 6400)
                       : (s == 1) ? (float)(16 * 3 * 1600)
                                  : (float)(16 * 3 * 400);
        const float n_noobj = Ns - nobj;
        const float lxywh = (sxy + swh) / fmaxf(2.f * nobj, 1.f);
        const float lcls  = scls / fmaxf(nobj * (float)NUM_CLASSES, 1.f);
        const float lpos  = spos / fmaxf(nobj, 1.f);
        const float lneg  = (negs + scor) / fmaxf(n_noobj, 1.f);
        const float has   = (nobj > 0.f) ? 1.f : 0.f;
        total += 5.f * lxywh * has + lpos * has + 0.5f * lneg + lcls * has;
    }
    out[0] = total / 3.f;

    // reset for the next call (all producers of THIS call provably done)
    #pragma unroll
    for (int c = 0; c < NCELLS; ++c)
        #pragma unroll
        for (int j = 0; j < NSTRIPE; ++j) st_llc(&g_acc[c][j][0], 0.f);
    #pragma unroll
    for (int k2 = 0; k2 < 8; ++k2)
        __hip_atomic_store(&g_cnt[k2][0], 0u, __ATOMIC_RELAXED,
                           __HIP_MEMORY_SCOPE_AGENT);
    __hip_atomic_store(&g_master[0], 0u, __ATOMIC_RELAXED,
                       __HIP_MEMORY_SCOPE_AGENT);
}

template<int NI, int PLANE4>
__device__ __forceinline__ float neg_sum(const float* __restrict__ P,
                                         int lq, int f) {
    float sum = 0.f;
    #pragma unroll
    for (int k = 0; k < 4; ++k) {
        const int idx = lq * 512 + k * 128 + f;
        if (idx < NI) {
            const int plane = idx / PLANE4;          // compile-time divisor
            const int r4 = idx - plane * PLANE4;
            const int b = plane / 3;
            const int a = plane - b * 3;
            const float4 v = *reinterpret_cast<const float4*>(
                P + (size_t)(b * 255 + a * 85 + 4) * (PLANE4 * 4)
                  + (size_t)r4 * 4);
            sum += focal0(v.x) + focal0(v.y) + focal0(v.z) + focal0(v.w);
        }
    }
    return sum;
}

__global__ __launch_bounds__(128)
void fused_kernel(const float* __restrict__ p0,
                  const float* __restrict__ p1,
                  const float* __restrict__ p2,
                  const float* __restrict__ tgt,
                  float* __restrict__ out) {
    __shared__ int   s_cell[32];
    __shared__ int   s_cls[32];
    __shared__ float s_sum[5];
    __shared__ float s_ns[2];

    const int bid = blockIdx.x;
    const int f   = threadIdx.x;          // 128 threads = 2 waves

    if (bid < OBJ_BLOCKS) {
        // ====== object path: one block per (scale, batch, target) ======
        // (R10-proven wide structure: 1 gather/thread = one latency round.)
        const int s = bid >> 9;            // /512
        const int r = bid & 511;
        const int b = r >> 5;              // /32
        const int t = r & 31;
        const int H  = (s == 0) ? 80 : (s == 1 ? 40 : 20);
        const int W  = H;
        const int HW = H * W;

        float aw0, aw1, aw2, ah0, ah1, ah2;
        if (s == 0) { aw0=10.f/640.f; aw1=16.f/640.f; aw2=33.f/640.f;
                      ah0=13.f/640.f; ah1=30.f/640.f; ah2=23.f/640.f; }
        else if (s == 1) { aw0=30.f/640.f; aw1=62.f/640.f; aw2=59.f/640.f;
                           ah0=61.f/640.f; ah1=45.f/640.f; ah2=119.f/640.f; }
        else { aw0=116.f/640.f; aw1=156.f/640.f; aw2=373.f/640.f;
               ah0=90.f/640.f;  ah1=198.f/640.f; ah2=326.f/640.f; }

        if (f < 5) s_sum[f] = 0.f;

        if (f < 32) {
            const float* tg = tgt + (size_t)(b * 32 + f) * 5;
            const float w = tg[3], h = tg[4];
            int cell = -1;
            if (w > 0.f && h > 0.f) {
                // argmax IoU over 3 anchors, first-max on ties (strict >)
                float best = -1.f; int ba = 0;
                float inter = fminf(w, aw0) * fminf(h, ah0);
                float iou = inter / (w * h + aw0 * ah0 - inter + 1e-6f);
                if (iou > best) { best = iou; ba = 0; }
                inter = fminf(w, aw1) * fminf(h, ah1);
                iou = inter / (w * h + aw1 * ah1 - inter + 1e-6f);
                if (iou > best) { best = iou; ba = 1; }
                inter = fminf(w, aw2) * fminf(h, ah2);
                iou = inter / (w * h + aw2 * ah2 - inter + 1e-6f);
                if (iou > best) { best = iou; ba = 2; }
                const float xw = tg[1] * (float)W, yh = tg[2] * (float)H;
                int gi = (int)xw; gi = min(max(gi, 0), W - 1); // trunc==astype(i32)
                int gj = (int)yh; gj = min(max(gj, 0), H - 1);
                cell = (ba * H + gj) * W + gi;                 // b uniform in block
            }
            s_cell[f] = cell;
            s_cls[f]  = (int)tg[0];
        }
        __syncthreads();

        const int mycell = s_cell[t];
        bool winner = (mycell >= 0);
        if (winner) {
            // numpy scatter = last-write-wins in t order within the batch
            #pragma unroll 1
            for (int t2 = t + 1; t2 < 32; ++t2)
                if (s_cell[t2] == mycell) { winner = false; break; }
        }
        // `winner` is block-uniform (depends only on bid)

        if (winner) {
            // class UNION over all targets hitting this cell
            unsigned um0 = 0, um1 = 0, um2 = 0;
            #pragma unroll 1
            for (int t2 = 0; t2 < 32; ++t2) {
                if (s_cell[t2] == mycell) {
                    const int c = s_cls[t2];
                    if (c < 32)      um0 |= 1u << c;
                    else if (c < 64) um1 |= 1u << (c - 32);
                    else             um2 |= 1u << (c - 64);
                }
            }

            // geometry of target t (uniform; recomputed by all lanes)
            const float* tg = tgt + (size_t)(b * 32 + t) * 5;
            const float w = tg[3], h = tg[4];
            float best = -1.f; int ba = 0;
            {
                float inter = fminf(w, aw0) * fminf(h, ah0);
                float iou = inter / (w * h + aw0 * ah0 - inter + 1e-6f);
                if (iou > best) { best = iou; ba = 0; }
                inter = fminf(w, aw1) * fminf(h, ah1);
                iou = inter / (w * h + aw1 * ah1 - inter + 1e-6f);
                if (iou > best) { best = iou; ba = 1; }
                inter = fminf(w, aw2) * fminf(h, ah2);
                iou = inter / (w * h + aw2 * ah2 - inter + 1e-6f);
                if (iou > best) { best = iou; ba = 2; }
            }
            const float aw = (ba == 0) ? aw0 : (ba == 1 ? aw1 : aw2);
            const float ah = (ba == 0) ? ah0 : (ba == 1 ? ah1 : ah2);
            const float xw = tg[1] * (float)W, yh = tg[2] * (float)H;
            int gi = (int)xw; gi = min(max(gi, 0), W - 1);
            int gj = (int)yh; gj = min(max(gj, 0), H - 1);

            if (f < 85) {
                const float* P = (s == 0) ? p0 : (s == 1 ? p1 : p2);
                const float val = P[(size_t)(b * 255 + ba * 85 + f) * HW
                                    + (size_t)gj * W + gi];
                float contrib; int cat;
                if (f == 0) {
                    const float d = sigmoidf_(val) - (xw - (float)gi);
                    contrib = d * d; cat = 0;
                } else if (f == 1) {
                    const float d = sigmoidf_(val) - (yh - (float)gj);
                    contrib = d * d; cat = 0;
                } else if (f == 2) {
                    const float e = val - logf(w / aw + 1e-6f);
                    contrib = e * e; cat = 1;
                } else if (f == 3) {
                    const float e = val - logf(h / ah + 1e-6f);
                    contrib = e * e; cat = 1;
                } else if (f == 4) {
                    contrib = focal1(val); cat = 3;
                    atomicAdd(&s_sum[4], -focal0(val)); // correction to all-cell neg
                } else {
                    const int c = f - 5;
                    const bool ts = (c < 32) ? ((um0 >> c) & 1)
                                  : (c < 64) ? ((um1 >> (c - 32)) & 1)
                                             : ((um2 >> (c - 64)) & 1);
                    contrib = ts ? focal1(val) : focal0(val); cat = 2;
                }
                atomicAdd(&s_sum[cat], contrib);
            }
        }
        __syncthreads();
        // lanes 0..5 issue the 6 adds as ONE predicated global_atomic
        // instruction (same wave as lane 0 -> finish_block's vmcnt(0)
        // covers them before the leaf-counter bump).
        if (winner && f < 6) {
            const float v = (f < 5) ? s_sum[f] : 1.0f;   // [5] = n_obj count
            atomicAdd(&g_acc[s * 7 + f][bid & 7][0], v);
        }
        if (f == 0) finish_block(bid, out);
    } else {
        // ================= all-cell negative path =================
        const int q = bid - OBJ_BLOCKS;              // 0..197
        int s; float sum;
        if (q < NEG0_BLOCKS) {
            s = 0; sum = neg_sum<76800, 1600>(p0, q, f);
        } else if (q < NEG0_BLOCKS + NEG1_BLOCKS) {
            s = 1; sum = neg_sum<19200, 400>(p1, q - NEG0_BLOCKS, f);
        } else {
            s = 2; sum = neg_sum<4800, 100>(p2, q - NEG0_BLOCKS - NEG1_BLOCKS, f);
        }
        #pragma unroll
        for (int off = 32; off; off >>= 1) sum += __shfl_down(sum, off, 64);
        if ((f & 63) == 0) s_ns[f >> 6] = sum;
        __syncthreads();
        if (f == 0) {
            atomicAdd(&g_acc[s * 7 + 6][bid & 7][0], s_ns[0] + s_ns[1]);
            finish_block(bid, out);
        }
    }
}

extern "C" void kernel_launch(void* const* d_in, const int* in_sizes, int n_in,
                              void* d_out, int out_size, void* d_ws, size_t ws_size,
                              hipStream_t stream) {
    const float* p0  = (const float*)d_in[0];
    const float* p1  = (const float*)d_in[1];
    const float* p2  = (const float*)d_in[2];
    const float* tgt = (const float*)d_in[3];
    float* out = (float*)d_out;
    (void)d_ws; (void)ws_size;

    fused_kernel<<<PRODUCERS, 128, 0, stream>>>(p0, p1, p2, tgt, out);
}

// Round 14
// 30.111 us; speedup vs baseline: 1.4499x; 1.4499x over previous
//
#include <hip/hip_runtime.h>
#include <math.h>

#define NUM_CLASSES 80
#define OBJ_BLOCKS 1536                 // 3 scales x 16 batch x 32 targets
#define NEG0_BLOCKS 150                 // 76800 float4 / 512 (exact)
#define NEG1_BLOCKS 38                  // ceil(19200 / 512)
#define NEG2_BLOCKS 10                  // ceil(4800 / 512)
#define NEG_BLOCKS (NEG0_BLOCKS + NEG1_BLOCKS + NEG2_BLOCKS)   // 198
#define PRODUCERS (OBJ_BLOCKS + NEG_BLOCKS)                    // 1734
#define NCELLS 21                       // 3 scales x {xy,wh,cls,pos,corr,nobj,neg}

// ---- math helpers (match jax.nn.log_sigmoid / sigmoid in f32) ----
__device__ __forceinline__ float softplusf_(float x) {
    return x > 0.f ? x + log1pf(expf(-x)) : log1pf(expf(x));
}
__device__ __forceinline__ float sigmoidf_(float x) {
    return 1.f / (1.f + expf(-x));
}
// focal_bce(x, t=0) = softplus(x) * sigmoid(x)^2
__device__ __forceinline__ float focal0(float x) {
    float s = sigmoidf_(x);
    return softplusf_(x) * s * s;
}
// focal_bce(x, t=1) = softplus(-x) * sigmoid(-x)^2
__device__ __forceinline__ float focal1(float x) {
    float s = sigmoidf_(-x);
    return softplusf_(-x) * s * s;
}

// Device-global accumulators. Module .bss: zero at load, NOT part of the
// poisoned ws; finalize kernel resets to 0 each call -> every call (first
// included) sees identical state. One 128B line per cell.
// NO completion protocol: the work->finalize kernel boundary is the barrier
// (implicit kernel-end release + kernel-begin acquire covers cross-XCD
// visibility). R7/R9/R13 lessons: counters, release fences and striping all
// cost more than the one dispatch boundary they replace. Fire-and-forget
// float atomicAdds (no return dep, no ordering) pipeline at the LLC.
__device__ float g_acc[NCELLS][32];     // only [c][0] used

template<int NI, int PLANE4>
__device__ __forceinline__ float neg_sum(const float* __restrict__ P,
                                         int lq, int f) {
    float sum = 0.f;
    #pragma unroll
    for (int k = 0; k < 4; ++k) {
        const int idx = lq * 512 + k * 128 + f;
        if (idx < NI) {
            const int plane = idx / PLANE4;          // compile-time divisor
            const int r4 = idx - plane * PLANE4;
            const int b = plane / 3;
            const int a = plane - b * 3;
            const float4 v = *reinterpret_cast<const float4*>(
                P + (size_t)(b * 255 + a * 85 + 4) * (PLANE4 * 4)
                  + (size_t)r4 * 4);
            sum += focal0(v.x) + focal0(v.y) + focal0(v.z) + focal0(v.w);
        }
    }
    return sum;
}

__global__ __launch_bounds__(128)
void work_kernel(const float* __restrict__ p0,
                 const float* __restrict__ p1,
                 const float* __restrict__ p2,
                 const float* __restrict__ tgt) {
    __shared__ int   s_cell[32];
    __shared__ int   s_cls[32];
    __shared__ float s_sum[5];
    __shared__ float s_ns[2];

    const int bid = blockIdx.x;
    const int f   = threadIdx.x;          // 128 threads = 2 waves

    if (bid < OBJ_BLOCKS) {
        // ====== object path: one block per (scale, batch, target) ======
        // (R10-proven wide structure: 1 gather/thread = one latency round,
        //  3072 waves of TLP. R11 showed consolidation kills this.)
        const int s = bid >> 9;            // /512
        const int r = bid & 511;
        const int b = r >> 5;              // /32
        const int t = r & 31;
        const int H  = (s == 0) ? 80 : (s == 1 ? 40 : 20);
        const int W  = H;
        const int HW = H * W;

        float aw0, aw1, aw2, ah0, ah1, ah2;
        if (s == 0) { aw0=10.f/640.f; aw1=16.f/640.f; aw2=33.f/640.f;
                      ah0=13.f/640.f; ah1=30.f/640.f; ah2=23.f/640.f; }
        else if (s == 1) { aw0=30.f/640.f; aw1=62.f/640.f; aw2=59.f/640.f;
                           ah0=61.f/640.f; ah1=45.f/640.f; ah2=119.f/640.f; }
        else { aw0=116.f/640.f; aw1=156.f/640.f; aw2=373.f/640.f;
               ah0=90.f/640.f;  ah1=198.f/640.f; ah2=326.f/640.f; }

        if (f < 5) s_sum[f] = 0.f;

        if (f < 32) {
            const float* tg = tgt + (size_t)(b * 32 + f) * 5;
            const float w = tg[3], h = tg[4];
            int cell = -1;
            if (w > 0.f && h > 0.f) {
                // argmax IoU over 3 anchors, first-max on ties (strict >)
                float best = -1.f; int ba = 0;
                float inter = fminf(w, aw0) * fminf(h, ah0);
                float iou = inter / (w * h + aw0 * ah0 - inter + 1e-6f);
                if (iou > best) { best = iou; ba = 0; }
                inter = fminf(w, aw1) * fminf(h, ah1);
                iou = inter / (w * h + aw1 * ah1 - inter + 1e-6f);
                if (iou > best) { best = iou; ba = 1; }
                inter = fminf(w, aw2) * fminf(h, ah2);
                iou = inter / (w * h + aw2 * ah2 - inter + 1e-6f);
                if (iou > best) { best = iou; ba = 2; }
                const float xw = tg[1] * (float)W, yh = tg[2] * (float)H;
                int gi = (int)xw; gi = min(max(gi, 0), W - 1); // trunc==astype(i32)
                int gj = (int)yh; gj = min(max(gj, 0), H - 1);
                cell = (ba * H + gj) * W + gi;                 // b uniform in block
            }
            s_cell[f] = cell;
            s_cls[f]  = (int)tg[0];
        }
        __syncthreads();

        const int mycell = s_cell[t];
        bool winner = (mycell >= 0);
        if (winner) {
            // numpy scatter = last-write-wins in t order within the batch
            #pragma unroll 1
            for (int t2 = t + 1; t2 < 32; ++t2)
                if (s_cell[t2] == mycell) { winner = false; break; }
        }
        // `winner` is block-uniform (depends only on bid)

        if (winner) {
            // class UNION over all targets hitting this cell
            unsigned um0 = 0, um1 = 0, um2 = 0;
            #pragma unroll 1
            for (int t2 = 0; t2 < 32; ++t2) {
                if (s_cell[t2] == mycell) {
                    const int c = s_cls[t2];
                    if (c < 32)      um0 |= 1u << c;
                    else if (c < 64) um1 |= 1u << (c - 32);
                    else             um2 |= 1u << (c - 64);
                }
            }

            // geometry of target t (uniform; recomputed by all lanes)
            const float* tg = tgt + (size_t)(b * 32 + t) * 5;
            const float w = tg[3], h = tg[4];
            float best = -1.f; int ba = 0;
            {
                float inter = fminf(w, aw0) * fminf(h, ah0);
                float iou = inter / (w * h + aw0 * ah0 - inter + 1e-6f);
                if (iou > best) { best = iou; ba = 0; }
                inter = fminf(w, aw1) * fminf(h, ah1);
                iou = inter / (w * h + aw1 * ah1 - inter + 1e-6f);
                if (iou > best) { best = iou; ba = 1; }
                inter = fminf(w, aw2) * fminf(h, ah2);
                iou = inter / (w * h + aw2 * ah2 - inter + 1e-6f);
                if (iou > best) { best = iou; ba = 2; }
            }
            const float aw = (ba == 0) ? aw0 : (ba == 1 ? aw1 : aw2);
            const float ah = (ba == 0) ? ah0 : (ba == 1 ? ah1 : ah2);
            const float xw = tg[1] * (float)W, yh = tg[2] * (float)H;
            int gi = (int)xw; gi = min(max(gi, 0), W - 1);
            int gj = (int)yh; gj = min(max(gj, 0), H - 1);

            if (f < 85) {
                const float* P = (s == 0) ? p0 : (s == 1 ? p1 : p2);
                const float val = P[(size_t)(b * 255 + ba * 85 + f) * HW
                                    + (size_t)gj * W + gi];
                float contrib; int cat;
                if (f == 0) {
                    const float d = sigmoidf_(val) - (xw - (float)gi);
                    contrib = d * d; cat = 0;
                } else if (f == 1) {
                    const float d = sigmoidf_(val) - (yh - (float)gj);
                    contrib = d * d; cat = 0;
                } else if (f == 2) {
                    const float e = val - logf(w / aw + 1e-6f);
                    contrib = e * e; cat = 1;
                } else if (f == 3) {
                    const float e = val - logf(h / ah + 1e-6f);
                    contrib = e * e; cat = 1;
                } else if (f == 4) {
                    contrib = focal1(val); cat = 3;
                    atomicAdd(&s_sum[4], -focal0(val)); // correction to all-cell neg
                } else {
                    const int c = f - 5;
                    const bool ts = (c < 32) ? ((um0 >> c) & 1)
                                  : (c < 64) ? ((um1 >> (c - 32)) & 1)
                                             : ((um2 >> (c - 64)) & 1);
                    contrib = ts ? focal1(val) : focal0(val); cat = 2;
                }
                atomicAdd(&s_sum[cat], contrib);
            }
        }
        __syncthreads();
        if (f == 0 && winner) {          // fire-and-forget, R12-proven
            atomicAdd(&g_acc[s * 7 + 0][0], s_sum[0]);
            atomicAdd(&g_acc[s * 7 + 1][0], s_sum[1]);
            atomicAdd(&g_acc[s * 7 + 2][0], s_sum[2]);
            atomicAdd(&g_acc[s * 7 + 3][0], s_sum[3]);
            atomicAdd(&g_acc[s * 7 + 4][0], s_sum[4]);
            atomicAdd(&g_acc[s * 7 + 5][0], 1.0f);   // n_obj
        }
    } else {
        // ================= all-cell negative path =================
        const int q = bid - OBJ_BLOCKS;              // 0..197
        int s; float sum;
        if (q < NEG0_BLOCKS) {
            s = 0; sum = neg_sum<76800, 1600>(p0, q, f);
        } else if (q < NEG0_BLOCKS + NEG1_BLOCKS) {
            s = 1; sum = neg_sum<19200, 400>(p1, q - NEG0_BLOCKS, f);
        } else {
            s = 2; sum = neg_sum<4800, 100>(p2, q - NEG0_BLOCKS - NEG1_BLOCKS, f);
        }
        #pragma unroll
        for (int off = 32; off; off >>= 1) sum += __shfl_down(sum, off, 64);
        if ((f & 63) == 0) s_ns[f >> 6] = sum;
        __syncthreads();
        if (f == 0) atomicAdd(&g_acc[s * 7 + 6][0], s_ns[0] + s_ns[1]);
    }
}

// ---- finalize: single thread; kernel boundary = completion barrier ----
__global__ void finalize_kernel(float* __restrict__ out) {
    float a[NCELLS];
    #pragma unroll
    for (int c = 0; c < NCELLS; ++c) a[c] = g_acc[c][0];   // pipelined loads

    float total = 0.f;
    #pragma unroll
    for (int s = 0; s < 3; ++s) {
        const float sxy  = a[s * 7 + 0];
        const float swh  = a[s * 7 + 1];
        const float scls = a[s * 7 + 2];
        const float spos = a[s * 7 + 3];
        const float scor = a[s * 7 + 4];
        const float nobj = a[s * 7 + 5];
        const float negs = a[s * 7 + 6];
        const float Ns = (s == 0) ? (float)(16 * 3 * 6400)
                       : (s == 1) ? (float)(16 * 3 * 1600)
                                  : (float)(16 * 3 * 400);
        const float n_noobj = Ns - nobj;
        const float lxywh = (sxy + swh) / fmaxf(2.f * nobj, 1.f);
        const float lcls  = scls / fmaxf(nobj * (float)NUM_CLASSES, 1.f);
        const float lpos  = spos / fmaxf(nobj, 1.f);
        const float lneg  = (negs + scor) / fmaxf(n_noobj, 1.f);
        const float has   = (nobj > 0.f) ? 1.f : 0.f;
        total += 5.f * lxywh * has + lpos * has + 0.5f * lneg + lcls * has;
    }
    out[0] = total / 3.f;

    // reset for next call (kernel-end writeback publishes the zeros before
    // any subsequent dispatch's atomics) -> replay-deterministic
    #pragma unroll
    for (int c = 0; c < NCELLS; ++c) g_acc[c][0] = 0.f;
}

extern "C" void kernel_launch(void* const* d_in, const int* in_sizes, int n_in,
                              void* d_out, int out_size, void* d_ws, size_t ws_size,
                              hipStream_t stream) {
    const float* p0  = (const float*)d_in[0];
    const float* p1  = (const float*)d_in[1];
    const float* p2  = (const float*)d_in[2];
    const float* tgt = (const float*)d_in[3];
    float* out = (float*)d_out;
    (void)d_ws; (void)ws_size;

    work_kernel<<<PRODUCERS, 128, 0, stream>>>(p0, p1, p2, tgt);
    finalize_kernel<<<1, 1, 0, stream>>>(out);
}